// Round 2
// baseline (148.326 us; speedup 1.0000x reference)
//
#include <hip/hip_runtime.h>
#include <cstdint>
#include <cstddef>

typedef short bf16x8 __attribute__((ext_vector_type(8)));
typedef float f32x4 __attribute__((ext_vector_type(4)));

__device__ __forceinline__ unsigned short f2bf(float f) {
    union { float f; uint32_t u; } v; v.f = f;
    uint32_t r = v.u + 0x7FFFu + ((v.u >> 16) & 1u);   // round-to-nearest-even
    return (unsigned short)(r >> 16);
}

__device__ __forceinline__ float bf2f(unsigned short u) {
    union { uint32_t u; float f; } v; v.u = (uint32_t)u << 16;
    return v.f;
}

// ---------------- prep: cast X to bf16  +  transpose-cast B ----------------

__global__ void prep_kernel(const float* __restrict__ X,
                            unsigned short* __restrict__ Xbf, int n4,
                            const float* __restrict__ B,
                            unsigned short* __restrict__ Bt, int H,
                            int castBlocks) {
    if ((int)blockIdx.x < castBlocks) {
        int i = blockIdx.x * 256 + threadIdx.x;
        if (i < n4) {
            float4 v = ((const float4*)X)[i];
            ushort4 o;
            o.x = f2bf(v.x); o.y = f2bf(v.y); o.z = f2bf(v.z); o.w = f2bf(v.w);
            ((ushort4*)Xbf)[i] = o;
        }
        return;
    }
    __shared__ float tile[32][33];
    int tb = blockIdx.x - castBlocks;
    int tilesPerRow = H / 32;
    int bx = (tb % tilesPerRow) * 32;   // n tile
    int by = (tb / tilesPerRow) * 32;   // k tile
    int tx = threadIdx.x & 31, ty = threadIdx.x >> 5;   // (32,8)
#pragma unroll
    for (int i = 0; i < 32; i += 8)
        tile[ty + i][tx] = B[(size_t)(by + ty + i) * H + bx + tx];
    __syncthreads();
#pragma unroll
    for (int i = 0; i < 32; i += 8)
        Bt[(size_t)(bx + ty + i) * H + by + tx] = f2bf(tile[tx][ty + i]);
}

// ---------------- tier-1: fused full-K GEMM + in-block scan ----------------
// 256x128 output tile, full K, grid (M/256)x(N/128) = 256 blocks (1/CU),
// 512 threads = 8 waves (wm 0..3 x wn 0..1), wave tile 64x64. Each block also
// computes the 8 rows BEFORE its tile (one extra MFMA fragment, +6% FLOP);
// since |a| <= 2^-5, an 8-row warm-up replay reconstructs the scan carry to
// ~1e-12 (same trick as scan_splitk_bf16) -> blocks are fully independent.
// A-tile = 264 rows (33 chunks of 8), B-tile = 128 rows (16 chunks).
// Staging: proven chunk layout: chunk c holds global rows c*8+srow, lane l
// -> slot l*16B with colblk (l&7)^(l>>3) XOR swizzle (0 bank conflicts).
// Epilogue: acc -> fp32 S in LDS (264x128x4 = 135168 B, reuses dead staging
// region), then 128 cols x 4 row-quarters scanned in-LDS, fp32 out written
// coalesced. Removes the scan kernel + 67 MB of S0/S1 HBM round-trip.

__global__ __launch_bounds__(512, 2) void gemm_scan_fused(
    const unsigned short* __restrict__ A,
    const unsigned short* __restrict__ Bt,
    const float* __restrict__ Ad,
    float* __restrict__ out,
    int M, int N, int K, int gridMt)
{
    extern __shared__ char smem[];   // 135168 B dynamic

    const int tid  = threadIdx.x;
    const int wave = tid >> 6;
    const int lane = tid & 63;

    int b = blockIdx.x;
    int mt, nt;
    if ((gridMt & 7) == 0) {
        int x = b & 7, g = b >> 3;
        int mPerX = gridMt >> 3;
        mt = x * mPerX + (g % mPerX);
        nt = g / mPerX;
    } else {
        mt = b % gridMt;
        nt = b / gridMt;
    }
    const int m0 = mt * 256;
    const int n0 = nt * 128;

    const int wm = wave >> 1;           // 0..3: 64-row group
    const int wn = wave & 1;            // 0..1: 64-col group
    const int srow = lane >> 3;
    const int scol = ((lane & 7) ^ srow) * 8;
    const int quad = lane >> 4;
    const int l16  = lane & 15;
    const int s7   = l16 & 7;
    const int koff0 = (quad ^ s7) * 16;
    const int koff1 = ((quad + 4) ^ s7) * 16;
    const int hi8  = l16 >> 3;

    f32x4 acc[4][4];
#pragma unroll
    for (int i = 0; i < 4; ++i)
#pragma unroll
        for (int j = 0; j < 4; ++j)
            acc[i][j] = (f32x4){0.f, 0.f, 0.f, 0.f};
    f32x4 wacc = (f32x4){0.f, 0.f, 0.f, 0.f};

    // A chunks 0..32 at smem[0..33791]; B chunks 0..15 at smem[33792..50175]
    for (int k0 = 0; k0 < K; k0 += 64) {
#pragma unroll
        for (int i = 0; i < 7; ++i) {
            const int t = wave + i * 8;
            if (t < 49) {
                const unsigned short* g;
                if (t < 33) {
                    int gr = m0 - 8 + t * 8 + srow;
                    if (gr < 0) gr = 0;                 // mt==0 warm-up clamp
                    g = A + (size_t)gr * K + (k0 + scol);
                } else {
                    const int gr = n0 + (t - 33) * 8 + srow;
                    g = Bt + (size_t)gr * K + (k0 + scol);
                }
                __builtin_amdgcn_global_load_lds(
                    (const __attribute__((address_space(1))) void*)g,
                    (__attribute__((address_space(3))) void*)(smem + t * 1024 + lane * 16),
                    16, 0, 0);
            }
        }
        __syncthreads();

#pragma unroll
        for (int kk = 0; kk < 2; ++kk) {
            const int co = kk ? koff1 : koff0;
            bf16x8 af[4], bfr[4], aw, bw;
            aw = *(const bf16x8*)(smem + hi8 * 1024 + s7 * 128 + co);
#pragma unroll
            for (int im = 0; im < 4; ++im)
                af[im] = *(const bf16x8*)(smem +
                    (1 + wm * 8 + im * 2 + hi8) * 1024 + s7 * 128 + co);
#pragma unroll
            for (int in = 0; in < 4; ++in)
                bfr[in] = *(const bf16x8*)(smem + 33792 +
                    (wn * 8 + in * 2 + hi8) * 1024 + s7 * 128 + co);
            bw = *(const bf16x8*)(smem + 33792 +
                    ((wn * 4 + wm) * 2 + hi8) * 1024 + s7 * 128 + co);
            wacc = __builtin_amdgcn_mfma_f32_16x16x32_bf16(aw, bw, wacc, 0, 0, 0);
#pragma unroll
            for (int im = 0; im < 4; ++im)
#pragma unroll
                for (int in = 0; in < 4; ++in)
                    acc[im][in] = __builtin_amdgcn_mfma_f32_16x16x32_bf16(
                        af[im], bfr[in], acc[im][in], 0, 0, 0);
        }
        __syncthreads();
    }

    // ---- epilogue: S (fp32) -> LDS rows 0..263 (row 8+r == global m0+r) ----
    float* Sl = (float*)smem;
#pragma unroll
    for (int im = 0; im < 4; ++im)
#pragma unroll
        for (int in = 0; in < 4; ++in) {
            const int col = wn * 64 + in * 16 + l16;
#pragma unroll
            for (int r = 0; r < 4; ++r) {
                const int row = 8 + wm * 64 + im * 16 + quad * 4 + r;
                Sl[row * 128 + col] = acc[im][in][r];
            }
        }
    if (quad < 2) {                      // warm-up rows 0..7 (quad 0..1)
        const int wcol = (wn * 4 + wm) * 16 + l16;
#pragma unroll
        for (int r = 0; r < 4; ++r)
            Sl[(quad * 4 + r) * 128 + wcol] = wacc[r];
    }
    __syncthreads();

    // ---- in-block scan: 128 cols x 4 row-quarters of 64 ----
    const int c = tid & 127;
    const int q = tid >> 7;
    const float aa = Ad[n0 + c];
    float y = 0.f;
    if (mt != 0 || q != 0) {
        const int wb = q * 64;           // LDS rows wb..wb+7 = 8 rows before
#pragma unroll
        for (int i = 0; i < 8; ++i)
            y = fmaf(aa, y, Sl[(wb + i) * 128 + c]);
    }
    const size_t ob = (size_t)(m0 + q * 64) * N + n0 + c;
    const float* Sr = Sl + (8 + q * 64) * 128 + c;
    for (int t = 0; t < 64; ++t) {
        y = fmaf(aa, y, Sr[t * 128]);
        out[ob + (size_t)t * N] = y;
    }
}

// ---------------- tier-2: 8-phase 256x256 split-K GEMM, bf16 out ------------

#define G8_FENCE __builtin_amdgcn_sched_barrier(0)
#define G8_BAR   __builtin_amdgcn_s_barrier()
#define G8_LGKM0 asm volatile("s_waitcnt lgkmcnt(0)" ::: "memory")
#define G8_VM4   asm volatile("s_waitcnt vmcnt(4)" ::: "memory")
#define G8_VM0   asm volatile("s_waitcnt vmcnt(0)" ::: "memory")

#define G8_STAGE(gbase, lbase, h, k0) do {                                    \
    const int c0_ = (h) * 16 + wave;                                          \
    const int c1_ = c0_ + 8;                                                  \
    __builtin_amdgcn_global_load_lds(                                         \
        (const __attribute__((address_space(1))) void*)                       \
            ((gbase) + (size_t)(c0_ * 8 + srow) * K + ((k0) + scol)),         \
        (__attribute__((address_space(3))) void*)                             \
            ((lbase) + c0_ * 1024 + lane * 16), 16, 0, 0);                    \
    __builtin_amdgcn_global_load_lds(                                         \
        (const __attribute__((address_space(1))) void*)                       \
            ((gbase) + (size_t)(c1_ * 8 + srow) * K + ((k0) + scol)),         \
        (__attribute__((address_space(3))) void*)                             \
            ((lbase) + c1_ * 1024 + lane * 16), 16, 0, 0);                    \
} while (0)

#define G8_LOAD_AF(buf, imh) do {                                             \
    const char* p_ = (const char*)(buf) + rA + (imh) * 8192;                  \
    af[0][0] = *(const bf16x8*)(p_ + 0 * 2048 + koff0);                       \
    af[0][1] = *(const bf16x8*)(p_ + 0 * 2048 + koff1);                       \
    af[1][0] = *(const bf16x8*)(p_ + 1 * 2048 + koff0);                       \
    af[1][1] = *(const bf16x8*)(p_ + 1 * 2048 + koff1);                       \
    af[2][0] = *(const bf16x8*)(p_ + 2 * 2048 + koff0);                       \
    af[2][1] = *(const bf16x8*)(p_ + 2 * 2048 + koff1);                       \
    af[3][0] = *(const bf16x8*)(p_ + 3 * 2048 + koff0);                       \
    af[3][1] = *(const bf16x8*)(p_ + 3 * 2048 + koff1);                       \
} while (0)

#define G8_LOAD_BF(buf, inh) do {                                             \
    const char* p_ = (const char*)(buf) + rB + (inh) * 4096;                  \
    bq[inh][0][0] = *(const bf16x8*)(p_ + 0 * 2048 + koff0);                  \
    bq[inh][0][1] = *(const bf16x8*)(p_ + 0 * 2048 + koff1);                  \
    bq[inh][1][0] = *(const bf16x8*)(p_ + 1 * 2048 + koff0);                  \
    bq[inh][1][1] = *(const bf16x8*)(p_ + 1 * 2048 + koff1);                  \
} while (0)

#define G8_MFMA(imh, inh) do {                                                \
    _Pragma("unroll")                                                         \
    for (int j_ = 0; j_ < 4; ++j_) {                                          \
        acc[(imh)*4+j_][(inh)*2+0] = __builtin_amdgcn_mfma_f32_16x16x32_bf16( \
            af[j_][0], bq[inh][0][0], acc[(imh)*4+j_][(inh)*2+0], 0, 0, 0);   \
        acc[(imh)*4+j_][(inh)*2+0] = __builtin_amdgcn_mfma_f32_16x16x32_bf16( \
            af[j_][1], bq[inh][0][1], acc[(imh)*4+j_][(inh)*2+0], 0, 0, 0);   \
        acc[(imh)*4+j_][(inh)*2+1] = __builtin_amdgcn_mfma_f32_16x16x32_bf16( \
            af[j_][0], bq[inh][1][0], acc[(imh)*4+j_][(inh)*2+1], 0, 0, 0);   \
        acc[(imh)*4+j_][(inh)*2+1] = __builtin_amdgcn_mfma_f32_16x16x32_bf16( \
            af[j_][1], bq[inh][1][1], acc[(imh)*4+j_][(inh)*2+1], 0, 0, 0);   \
    }                                                                         \
} while (0)

#define G8_TAIL(MF, VMW) do {                                                 \
    G8_FENCE;                                                                 \
    G8_BAR;                                                                   \
    G8_LGKM0; G8_FENCE;                                                       \
    __builtin_amdgcn_s_setprio(1);                                            \
    MF;                                                                       \
    __builtin_amdgcn_s_setprio(0);                                            \
    G8_FENCE; VMW;                                                            \
    G8_BAR;                                                                   \
    asm volatile("" ::: "memory");                                            \
    G8_FENCE;                                                                 \
} while (0)

__global__ __launch_bounds__(512, 2) void gemm_8ph_bf16out(
    const unsigned short* __restrict__ A,
    const unsigned short* __restrict__ Bt,
    unsigned short* __restrict__ S0, unsigned short* __restrict__ S1,
    int M, int N, int K, int gridM2, int gridN2)
{
    extern __shared__ char smem[];   // 131072 B dynamic

    const int tid  = threadIdx.x;
    const int wave = tid >> 6;
    const int lane = tid & 63;

    int b = blockIdx.x;
    int mt, nt, kt;
    if ((gridM2 & 7) == 0) {
        int x = b & 7, g = b >> 3;
        int mPerX = gridM2 >> 3;
        int ml = g % mPerX, g2 = g / mPerX;
        nt = g2 % gridN2;
        kt = g2 / gridN2;
        mt = x * mPerX + ml;
    } else {
        mt = b % gridM2;
        nt = (b / gridM2) % gridN2;
        kt = b / (gridM2 * gridN2);
    }
    const int m0 = mt * 256;
    const int n0 = nt * 256;
    const int ksize = K >> 1;
    const int kbase = kt * ksize;
    const int NT = ksize >> 6;
    const int NI = NT >> 1;

    const int wm = wave >> 2;
    const int wn = wave & 3;
    const int srow = lane >> 3;
    const int scol = ((lane & 7) ^ srow) * 8;
    const int quad = lane >> 4;
    const int l16  = lane & 15;
    const int s7   = l16 & 7;
    const int rA = (wm * 16 + (l16 >> 3)) * 1024 + s7 * 128;
    const int rB = (wn * 8  + (l16 >> 3)) * 1024 + s7 * 128;
    const int koff0 = (quad ^ s7) * 16;
    const int koff1 = ((quad + 4) ^ s7) * 16;

    char* const A0L = smem;
    char* const A1L = smem + 32768;
    char* const B0L = smem + 65536;
    char* const B1L = smem + 98304;

    const unsigned short* const Ag = A  + (size_t)m0 * K;
    const unsigned short* const Bg = Bt + (size_t)n0 * K;

    f32x4 acc[8][4];
#pragma unroll
    for (int i = 0; i < 8; ++i)
#pragma unroll
        for (int j = 0; j < 4; ++j)
            acc[i][j] = (f32x4){0.f, 0.f, 0.f, 0.f};
    bf16x8 af[4][2];
    bf16x8 bq[2][2][2];

    G8_STAGE(Bg, B0L, 0, kbase);
    G8_STAGE(Bg, B0L, 1, kbase);
    G8_STAGE(Ag, A0L, 0, kbase);
    G8_STAGE(Ag, A0L, 1, kbase);
    G8_STAGE(Bg, B1L, 0, kbase + 64);
    G8_STAGE(Bg, B1L, 1, kbase + 64);
    G8_FENCE; G8_VM4;
    G8_BAR;
    asm volatile("" ::: "memory");
    G8_FENCE;

#pragma unroll 1
    for (int it = 0; it < NI; ++it) {
        const int c0t = it * 2;
        int t1 = c0t + 1; if (t1 > NT - 1) t1 = NT - 1;
        int t2 = c0t + 2; if (t2 > NT - 1) t2 = NT - 1;
        int t3 = c0t + 3; if (t3 > NT - 1) t3 = NT - 1;
        const int k1 = kbase + t1 * 64;
        const int k2 = kbase + t2 * 64;
        const int k3 = kbase + t3 * 64;

        G8_LOAD_AF(A0L, 0);
        G8_LOAD_BF(B0L, 0);
        G8_STAGE(Ag, A1L, 0, k1);
        G8_TAIL(G8_MFMA(0, 0), (void)0);
        G8_LOAD_BF(B0L, 1);
        G8_STAGE(Ag, A1L, 1, k1);
        G8_TAIL(G8_MFMA(0, 1), (void)0);
        G8_LOAD_AF(A0L, 1);
        G8_STAGE(Bg, B0L, 0, k2);
        G8_TAIL(G8_MFMA(1, 1), (void)0);
        G8_STAGE(Bg, B0L, 1, k2);
        G8_TAIL(G8_MFMA(1, 0), G8_VM4);

        G8_LOAD_AF(A1L, 0);
        G8_LOAD_BF(B1L, 0);
        G8_STAGE(Ag, A0L, 0, k2);
        G8_TAIL(G8_MFMA(0, 0), (void)0);
        G8_LOAD_BF(B1L, 1);
        G8_STAGE(Ag, A0L, 1, k2);
        G8_TAIL(G8_MFMA(0, 1), (void)0);
        G8_LOAD_AF(A1L, 1);
        G8_STAGE(Bg, B1L, 0, k3);
        G8_TAIL(G8_MFMA(1, 1), (void)0);
        G8_STAGE(Bg, B1L, 1, k3);
        G8_TAIL(G8_MFMA(1, 0), G8_VM4);
    }

    G8_VM0;

    unsigned short* __restrict__ S = (kt == 0) ? S0 : S1;
#pragma unroll
    for (int im = 0; im < 8; ++im) {
#pragma unroll
        for (int in = 0; in < 4; ++in) {
            const int col = n0 + wn * 64 + in * 16 + l16;
#pragma unroll
            for (int r = 0; r < 4; ++r) {
                const int row = m0 + wm * 128 + im * 16 + quad * 4 + r;
                S[(size_t)row * N + col] = f2bf(acc[im][in][r]);
            }
        }
    }
}

// ---------------- tier-3 GEMM: 256x128, split-K=2, bf16 out (proven) --------

__global__ __launch_bounds__(256, 2) void gemm_sk_bf16out(
    const unsigned short* __restrict__ A,
    const unsigned short* __restrict__ Bt,
    unsigned short* __restrict__ S0, unsigned short* __restrict__ S1,
    int M, int N, int K, int gridM, int gridN)
{
    __shared__ __attribute__((aligned(16))) unsigned short sA[256 * 64];
    __shared__ __attribute__((aligned(16))) unsigned short sB[128 * 64];

    const int tid  = threadIdx.x;
    const int wave = tid >> 6;
    const int lane = tid & 63;

    int b = blockIdx.x;
    int mt, nt, kt;
    if ((gridM & 7) == 0) {
        int x = b & 7, g = b >> 3;
        int mPerX = gridM >> 3;
        int ml = g % mPerX, g2 = g / mPerX;
        nt = g2 % gridN;
        kt = g2 / gridN;
        mt = x * mPerX + ml;
    } else {
        mt = b % gridM;
        nt = (b / gridM) % gridN;
        kt = b / (gridM * gridN);
    }
    const int m0 = mt * 256;
    const int n0 = nt * 128;
    const int ksize = K / 2;
    const int kbase = kt * ksize;

    const int srow = lane >> 3;
    const int scol = ((lane & 7) ^ srow) * 8;

    const int quad = lane >> 4;
    const int l16  = lane & 15;
    const int wm = wave >> 1;
    const int wn = wave & 1;
    const int s7 = l16 & 7;
    const int c0 = (quad ^ s7) * 16;
    const int c1 = ((quad + 4) ^ s7) * 16;

    f32x4 acc[8][4];
#pragma unroll
    for (int i = 0; i < 8; ++i)
#pragma unroll
        for (int j = 0; j < 4; ++j)
            acc[i][j] = (f32x4){0.f, 0.f, 0.f, 0.f};

    const unsigned short* Ab = A  + (size_t)m0 * K;
    const unsigned short* Bb = Bt + (size_t)n0 * K;

    const int rA = (wm * 16 + (l16 >> 3)) * 1024 + s7 * 128;
    const int rB = (wn * 8  + (l16 >> 3)) * 1024 + s7 * 128;

    for (int k0 = kbase; k0 < kbase + ksize; k0 += 64) {
#pragma unroll
        for (int i = 0; i < 8; ++i) {
            const int t = wave * 8 + i;
            const unsigned short* ga = Ab + (size_t)(t * 8 + srow) * K + (k0 + scol);
            __builtin_amdgcn_global_load_lds(
                (const __attribute__((address_space(1))) void*)ga,
                (__attribute__((address_space(3))) void*)(sA + t * 512),
                16, 0, 0);
        }
#pragma unroll
        for (int i = 0; i < 4; ++i) {
            const int t = wave * 4 + i;
            const unsigned short* gb = Bb + (size_t)(t * 8 + srow) * K + (k0 + scol);
            __builtin_amdgcn_global_load_lds(
                (const __attribute__((address_space(1))) void*)gb,
                (__attribute__((address_space(3))) void*)(sB + t * 512),
                16, 0, 0);
        }
        __syncthreads();

#pragma unroll
        for (int kk = 0; kk < 2; ++kk) {
            const int co = kk ? c1 : c0;
            bf16x8 af[8], bfr[4];
#pragma unroll
            for (int im = 0; im < 8; ++im)
                af[im] = *(const bf16x8*)((const char*)sA + rA + im * 2048 + co);
#pragma unroll
            for (int in = 0; in < 4; ++in)
                bfr[in] = *(const bf16x8*)((const char*)sB + rB + in * 2048 + co);
#pragma unroll
            for (int im = 0; im < 8; ++im)
#pragma unroll
                for (int in = 0; in < 4; ++in)
                    acc[im][in] = __builtin_amdgcn_mfma_f32_16x16x32_bf16(
                        af[im], bfr[in], acc[im][in], 0, 0, 0);
        }
        __syncthreads();
    }

    unsigned short* __restrict__ S = (kt == 0) ? S0 : S1;
#pragma unroll
    for (int im = 0; im < 8; ++im) {
#pragma unroll
        for (int in = 0; in < 4; ++in) {
            int col = n0 + wn * 64 + in * 16 + l16;
#pragma unroll
            for (int r = 0; r < 4; ++r) {
                int row = m0 + wm * 128 + im * 16 + quad * 4 + r;
                S[(size_t)row * N + col] = f2bf(acc[im][in][r]);
            }
        }
    }
}

// ---------------- mid-tier GEMM (fp32 out, non-split; round-3 proven) -------

__device__ __forceinline__ void stage_tile128(
    const unsigned short* __restrict__ Ab, const unsigned short* __restrict__ Bb,
    unsigned short* sAp, unsigned short* sBp,
    int wave, int srow, int scol, int k0, int K)
{
#pragma unroll
    for (int i = 0; i < 4; ++i) {
        const int t = wave * 4 + i;
        const unsigned short* ga = Ab + (size_t)(t * 8 + srow) * K + (k0 + scol);
        __builtin_amdgcn_global_load_lds(
            (const __attribute__((address_space(1))) void*)ga,
            (__attribute__((address_space(3))) void*)(sAp + t * 512),
            16, 0, 0);
        const unsigned short* gb = Bb + (size_t)(t * 8 + srow) * K + (k0 + scol);
        __builtin_amdgcn_global_load_lds(
            (const __attribute__((address_space(1))) void*)gb,
            (__attribute__((address_space(3))) void*)(sBp + t * 512),
            16, 0, 0);
    }
}

__global__ __launch_bounds__(256, 4) void gemm_f32out(
    const unsigned short* __restrict__ A,
    const unsigned short* __restrict__ Bt,
    float* __restrict__ C, int M, int N, int K, int gridM)
{
    __shared__ __attribute__((aligned(16))) unsigned short sA[128 * 64];
    __shared__ __attribute__((aligned(16))) unsigned short sB[128 * 64];

    const int tid  = threadIdx.x;
    const int wave = tid >> 6;
    const int lane = tid & 63;

    int b = blockIdx.x;
    int mt, nt;
    if ((gridM & 7) == 0) {
        int x = b & 7, g = b >> 3;
        int mPerX = gridM >> 3;
        mt = x * mPerX + (g % mPerX);
        nt = g / mPerX;
    } else {
        mt = b % gridM;
        nt = b / gridM;
    }
    const int m0 = mt * 128;
    const int n0 = nt * 128;

    const int srow = lane >> 3;
    const int scol = ((lane & 7) ^ srow) * 8;
    const int quad = lane >> 4;
    const int l16  = lane & 15;
    const int wm = wave >> 1;
    const int wn = wave & 1;
    const int s7 = l16 & 7;
    const int rbaseA = (wm * 8 + (l16 >> 3)) * 1024 + s7 * 128;
    const int rbaseB = (wn * 8 + (l16 >> 3)) * 1024 + s7 * 128;
    const int coff0 = (quad ^ s7) * 16;
    const int coff1 = ((quad + 4) ^ s7) * 16;

    f32x4 acc[4][4];
#pragma unroll
    for (int i = 0; i < 4; ++i)
#pragma unroll
        for (int j = 0; j < 4; ++j)
            acc[i][j] = (f32x4){0.f, 0.f, 0.f, 0.f};

    const unsigned short* Ab = A  + (size_t)m0 * K;
    const unsigned short* Bb = Bt + (size_t)n0 * K;

    for (int k0 = 0; k0 < K; k0 += 64) {
        stage_tile128(Ab, Bb, sA, sB, wave, srow, scol, k0, K);
        __syncthreads();
        bf16x8 af[2][4], bfr[2][4];
#pragma unroll
        for (int t = 0; t < 4; ++t) {
            const char* pa = (const char*)sA + rbaseA + t * 2048;
            af[0][t]  = *(const bf16x8*)(pa + coff0);
            af[1][t]  = *(const bf16x8*)(pa + coff1);
            const char* pb = (const char*)sB + rbaseB + t * 2048;
            bfr[0][t] = *(const bf16x8*)(pb + coff0);
            bfr[1][t] = *(const bf16x8*)(pb + coff1);
        }
#pragma unroll
        for (int kk = 0; kk < 2; ++kk)
#pragma unroll
            for (int im = 0; im < 4; ++im)
#pragma unroll
                for (int in = 0; in < 4; ++in)
                    acc[im][in] = __builtin_amdgcn_mfma_f32_16x16x32_bf16(
                        af[kk][im], bfr[kk][in], acc[im][in], 0, 0, 0);
        __syncthreads();
    }

#pragma unroll
    for (int im = 0; im < 4; ++im)
#pragma unroll
        for (int in = 0; in < 4; ++in) {
            int col = n0 + wn * 64 + in * 16 + l16;
#pragma unroll
            for (int r = 0; r < 4; ++r) {
                int row = m0 + wm * 64 + im * 16 + quad * 4 + r;
                C[(size_t)row * N + col] = acc[im][in][r];
            }
        }
}

// ---------------- scan (split-K fallback path) ----------------

__global__ void scan_splitk_bf16(const unsigned short* __restrict__ S0,
                                 const unsigned short* __restrict__ S1,
                                 const float* __restrict__ a_diag,
                                 float* __restrict__ out,
                                 int H2, int chunk) {
    int tid = blockIdx.x * blockDim.x + threadIdx.x;
    int hp = tid % H2, c = tid / H2;
    float2 av = ((const float2*)a_diag)[hp];
    const ushort2* S0v = (const ushort2*)S0;
    const ushort2* S1v = (const ushort2*)S1;
    float2* outv = (float2*)out;

    float y0 = 0.f, y1 = 0.f;
    if (c > 0) {
        size_t r0 = (size_t)c * chunk - 8;
#pragma unroll
        for (int i = 0; i < 8; ++i) {
            size_t idx = (r0 + i) * H2 + hp;
            ushort2 u = S0v[idx], w = S1v[idx];
            y0 = fmaf(av.x, y0, bf2f(u.x) + bf2f(w.x));
            y1 = fmaf(av.y, y1, bf2f(u.y) + bf2f(w.y));
        }
    }
    size_t idx = (size_t)c * chunk * H2 + hp;
    ushort2 u = S0v[idx], w = S1v[idx];
    for (int t = 0; t < chunk - 1; ++t) {
        size_t idx2 = idx + H2;
        ushort2 un = S0v[idx2], wn = S1v[idx2];
        y0 = fmaf(av.x, y0, bf2f(u.x) + bf2f(w.x));
        y1 = fmaf(av.y, y1, bf2f(u.y) + bf2f(w.y));
        outv[idx] = make_float2(y0, y1);
        u = un; w = wn; idx = idx2;
    }
    y0 = fmaf(av.x, y0, bf2f(u.x) + bf2f(w.x));
    y1 = fmaf(av.y, y1, bf2f(u.y) + bf2f(w.y));
    outv[idx] = make_float2(y0, y1);
}

// ---------------- mid-tier scan (fp32 S in out, in-place) --------------

__global__ void scan_init_kernel(const float* __restrict__ S,
                                 const float* __restrict__ a_diag,
                                 float* __restrict__ yinit,
                                 int H, int chunk, int W) {
    int tid = blockIdx.x * blockDim.x + threadIdx.x;
    int h = tid % H, c = tid / H;
    float a = a_diag[h];
    float y = 0.f;
    if (c > 0) {
        int t0 = c * chunk;
        for (int t = t0 - W; t < t0; ++t)
            y = fmaf(a, y, S[(size_t)t * H + h]);
    }
    yinit[(size_t)c * H + h] = y;
}

__global__ void scan_run_kernel(const float* __restrict__ yinit,
                                const float* __restrict__ a_diag,
                                float* __restrict__ out,
                                int H, int chunk) {
    int tid = blockIdx.x * blockDim.x + threadIdx.x;
    int h = tid % H, c = tid / H;
    float a = a_diag[h];
    float y = yinit[(size_t)c * H + h];
    size_t base = (size_t)c * chunk * H + h;
    float s = out[base];
#pragma unroll 4
    for (int t = 0; t < chunk - 1; ++t) {
        float snext = out[base + (size_t)(t + 1) * H];
        y = fmaf(a, y, s);
        out[base + (size_t)t * H] = y;
        s = snext;
    }
    y = fmaf(a, y, s);
    out[base + (size_t)(chunk - 1) * H] = y;
}

// ---------------- fallback (tiny ws): correct but slow ----------------

__global__ void gemm_fallback(const float* __restrict__ X, const float* __restrict__ B,
                              float* __restrict__ C, int M, int N, int K) {
    __shared__ float sA[16][17];
    __shared__ float sB[16][17];
    int tx = threadIdx.x, ty = threadIdx.y;
    int row = blockIdx.y * 16 + ty, col = blockIdx.x * 16 + tx;
    float acc = 0.f;
    for (int k0 = 0; k0 < K; k0 += 16) {
        sA[ty][tx] = (row < M && k0 + tx < K) ? X[(size_t)row * K + k0 + tx] : 0.f;
        sB[ty][tx] = (k0 + ty < K && col < N) ? B[(size_t)(k0 + ty) * N + col] : 0.f;
        __syncthreads();
#pragma unroll
        for (int kk = 0; kk < 16; ++kk) acc += sA[ty][kk] * sB[kk][tx];
        __syncthreads();
    }
    if (row < M && col < N) C[(size_t)row * N + col] = acc;
}

__global__ void scan_serial(float* __restrict__ out, const float* __restrict__ a_diag,
                            int T, int H) {
    int h = blockIdx.x * blockDim.x + threadIdx.x;
    if (h >= H) return;
    float a = a_diag[h], y = 0.f;
    for (int t = 0; t < T; ++t) {
        y = fmaf(a, y, out[(size_t)t * H + h]);
        out[(size_t)t * H + h] = y;
    }
}

// ---------------- launch ----------------

extern "C" void kernel_launch(void* const* d_in, const int* in_sizes, int n_in,
                              void* d_out, int out_size, void* d_ws, size_t ws_size,
                              hipStream_t stream) {
    const float* x = (const float*)d_in[0];   // (T,H)
    const float* a = (const float*)d_in[1];   // (H,)
    const float* b = (const float*)d_in[2];   // (H,H)
    float* out = (float*)d_out;               // (T,H)

    const int H = in_sizes[1];
    const int T = in_sizes[0] / H;
    const int M = T, N = H, K = H;

    const int CHUNK = 16, W = 12;

    size_t xbf_elems = (size_t)M * K;
    size_t bt_elems  = (size_t)N * K;
    size_t MN = (size_t)M * N;
    int nchunks = (T % CHUNK == 0) ? T / CHUNK : 0;

    size_t need_fused = (xbf_elems + bt_elems) * 2 + 256;
    size_t need_sk  = (xbf_elems + bt_elems + 2 * MN) * 2 + 256;
    size_t need_mid = xbf_elems * 2 + bt_elems * 2 + 256;

    bool shape_ok = (M % 128 == 0) && (N % 128 == 0) && (K % 128 == 0) &&
                    (H % 32 == 0) && nchunks > 0 && ((xbf_elems % 4) == 0) &&
                    (((size_t)nchunks * H) % 256 == 0);
    int gridMf = M / 128;
    int gridM  = (M % 256 == 0) ? M / 256 : 0;
    int gridN  = N / 128;
    int gridM8 = (M % 256 == 0) ? M / 256 : 0;
    int gridN8 = (N % 256 == 0) ? N / 256 : 0;
    bool k8ok  = (K % 256 == 0) && (K >= 256);

    int n4 = (int)(xbf_elems / 4);
    int castBlocks = (n4 + 255) / 256;
    int transBlocks = (H % 32 == 0) ? (H / 32) * (H / 32) : 0;

    int H2 = H / 2;
    size_t nth2 = (size_t)nchunks * H2;

    bool fused_ok = (M % 256 == 0) && (N % 128 == 0) && (K % 64 == 0) &&
                    (H % 32 == 0) && ((xbf_elems % 4) == 0) &&
                    ws_size >= need_fused;

    if (fused_ok) {
        // tier-1: fused full-K GEMM + in-block scan (no S materialization)
        unsigned short* Xbf = (unsigned short*)d_ws;
        unsigned short* Bt  = Xbf + xbf_elems;

        static bool gfattr = false;
        if (!gfattr) {
            (void)hipFuncSetAttribute((const void*)gemm_scan_fused,
                                      hipFuncAttributeMaxDynamicSharedMemorySize,
                                      135168);
            gfattr = true;
        }

        prep_kernel<<<castBlocks + transBlocks, 256, 0, stream>>>(
            x, Xbf, n4, b, Bt, H, castBlocks);

        gemm_scan_fused<<<(M / 256) * (N / 128), 512, 135168, stream>>>(
            Xbf, Bt, a, out, M, N, K, M / 256);
    } else if (shape_ok && gridM8 > 0 && gridN8 > 0 && k8ok && (H % 4 == 0) &&
               (nth2 % 256 == 0) && ws_size >= need_sk) {
        // tier-2: 256x256 8-phase tiles, split-K=2, bf16 partials
        unsigned short* Xbf = (unsigned short*)d_ws;
        unsigned short* Bt  = Xbf + xbf_elems;
        unsigned short* S0  = Bt + bt_elems;
        unsigned short* S1  = S0 + MN;

        static bool g8attr = false;
        if (!g8attr) {
            (void)hipFuncSetAttribute((const void*)gemm_8ph_bf16out,
                                      hipFuncAttributeMaxDynamicSharedMemorySize,
                                      131072);
            g8attr = true;
        }

        prep_kernel<<<castBlocks + transBlocks, 256, 0, stream>>>(
            x, Xbf, n4, b, Bt, H, castBlocks);

        gemm_8ph_bf16out<<<gridM8 * gridN8 * 2, 512, 131072, stream>>>(
            Xbf, Bt, S0, S1, M, N, K, gridM8, gridN8);

        scan_splitk_bf16<<<(int)(nth2 / 256), 256, 0, stream>>>(
            S0, S1, a, out, H2, CHUNK);
    } else if (shape_ok && gridM > 0 && (gridM % 8 == 0) && (H % 4 == 0) &&
               (nth2 % 256 == 0) && ws_size >= need_sk) {
        // tier-3: 256x128 tiles, split-K=2, bf16 partials, race-free scan
        unsigned short* Xbf = (unsigned short*)d_ws;
        unsigned short* Bt  = Xbf + xbf_elems;
        unsigned short* S0  = Bt + bt_elems;
        unsigned short* S1  = S0 + MN;

        prep_kernel<<<castBlocks + transBlocks, 256, 0, stream>>>(
            x, Xbf, n4, b, Bt, H, castBlocks);

        gemm_sk_bf16out<<<gridM * gridN * 2, 256, 0, stream>>>(
            Xbf, Bt, S0, S1, M, N, K, gridM, gridN);

        scan_splitk_bf16<<<(int)(nth2 / 256), 256, 0, stream>>>(
            S0, S1, a, out, H2, CHUNK);
    } else if (shape_ok && ws_size >= need_mid &&
               ((size_t)nchunks * H * 4 <= xbf_elems * 2)) {
        unsigned short* Xbf = (unsigned short*)d_ws;
        unsigned short* Bt  = Xbf + xbf_elems;
        float* yinit = (float*)d_ws;   // aliases Xbf: dead after gemm reads it

        prep_kernel<<<castBlocks + transBlocks, 256, 0, stream>>>(
            x, Xbf, n4, b, Bt, H, castBlocks);

        gemm_f32out<<<gridMf * gridN, 256, 0, stream>>>(
            Xbf, Bt, out, M, N, K, gridMf);

        int nth = nchunks * H;
        scan_init_kernel<<<nth / 256, 256, 0, stream>>>(out, a, yinit, H, CHUNK, W);
        scan_run_kernel<<<nth / 256, 256, 0, stream>>>(yinit, a, out, H, CHUNK);
    } else {
        dim3 tb(16, 16), tg((N + 15) / 16, (M + 15) / 16);
        gemm_fallback<<<tg, tb, 0, stream>>>(x, b, out, M, N, K);
        scan_serial<<<(H + 255) / 256, 256, 0, stream>>>(out, a, T, H);
    }
}

// Round 4
// 137.281 us; speedup vs baseline: 1.0805x; 1.0805x over previous
//
#include <hip/hip_runtime.h>
#include <cstdint>
#include <cstddef>

typedef short bf16x8 __attribute__((ext_vector_type(8)));
typedef float f32x4 __attribute__((ext_vector_type(4)));

__device__ __forceinline__ unsigned short f2bf(float f) {
    union { float f; uint32_t u; } v; v.f = f;
    uint32_t r = v.u + 0x7FFFu + ((v.u >> 16) & 1u);   // round-to-nearest-even
    return (unsigned short)(r >> 16);
}

__device__ __forceinline__ float bf2f(unsigned short u) {
    union { uint32_t u; float f; } v; v.u = (uint32_t)u << 16;
    return v.f;
}

// ---------------- prep: cast X to bf16  +  transpose-cast B ----------------

__global__ void prep_kernel(const float* __restrict__ X,
                            unsigned short* __restrict__ Xbf, int n4,
                            const float* __restrict__ B,
                            unsigned short* __restrict__ Bt, int H,
                            int castBlocks) {
    if ((int)blockIdx.x < castBlocks) {
        int i = blockIdx.x * 256 + threadIdx.x;
        if (i < n4) {
            float4 v = ((const float4*)X)[i];
            ushort4 o;
            o.x = f2bf(v.x); o.y = f2bf(v.y); o.z = f2bf(v.z); o.w = f2bf(v.w);
            ((ushort4*)Xbf)[i] = o;
        }
        return;
    }
    __shared__ float tile[32][33];
    int tb = blockIdx.x - castBlocks;
    int tilesPerRow = H / 32;
    int bx = (tb % tilesPerRow) * 32;   // n tile
    int by = (tb / tilesPerRow) * 32;   // k tile
    int tx = threadIdx.x & 31, ty = threadIdx.x >> 5;   // (32,8)
#pragma unroll
    for (int i = 0; i < 32; i += 8)
        tile[ty + i][tx] = B[(size_t)(by + ty + i) * H + bx + tx];
    __syncthreads();
#pragma unroll
    for (int i = 0; i < 32; i += 8)
        Bt[(size_t)(bx + ty + i) * H + by + tx] = f2bf(tile[tx][ty + i]);
}

// ---------------- tier-1: fused full-K GEMM + in-block scan (v2) ------------
// R2 counters: fusion validated (WRITE_SIZE = out only, HBM 7-16%) but
// MfmaUtil 23.9% / Occupancy 18.9% -> 57us: 256-tile grid = 1 block/CU with a
// single-buffered vmcnt(0)-drain loop left no co-resident block to hide the
// barrier stall. v2: 128x128 tile -> grid 512 = 2 blocks/CU (proven tier-3
// overlap regime); double-buffered staging with ONE barrier per K-step (stage
// t+1 issued before compute t, m248 2-phase pattern); bf16 S epilogue with
// stride-132 pad (conflict-free quad writes) -> LDS 2*33792 = 67584 B.
// Warm-up: 8 rows before the tile as one half-used MFMA fragment; |a| <= 2^-5
// so an 8-row replay reconstructs the scan carry to ~1e-12.
// A-tile = 136 rows = 17 chunks; B-tile = 128 rows = 16 chunks; 33 chunks of
// 1KB per buffer, proven XOR-swizzle chunk layout (0 conflicts).
// Race audit: stage(t+1) targets buffer (t+1)&1 whose last readers ran
// before iter t-1's closing __syncthreads (which drains vmcnt(0)); OK.

__global__ __launch_bounds__(256, 2) void gemm_scan_fused(
    const unsigned short* __restrict__ A,
    const unsigned short* __restrict__ Bt,
    const float* __restrict__ Ad,
    float* __restrict__ out,
    int M, int N, int K, int gridMt)
{
    extern __shared__ char smem[];   // 67584 B dynamic (2 x 33 chunks)

    const int tid  = threadIdx.x;
    const int wave = tid >> 6;
    const int lane = tid & 63;

    int b = blockIdx.x;
    int mt, nt;
    if ((gridMt & 7) == 0) {
        int x = b & 7, g = b >> 3;
        int mPerX = gridMt >> 3;
        mt = x * mPerX + (g % mPerX);
        nt = g / mPerX;
    } else {
        mt = b % gridMt;
        nt = b / gridMt;
    }
    const int m0 = mt * 128;
    const int n0 = nt * 128;

    const int wm = wave >> 1;           // 0..1: 64-row group
    const int wn = wave & 1;            // 0..1: 64-col group
    const int srow = lane >> 3;
    const int scol = ((lane & 7) ^ srow) * 8;
    const int quad = lane >> 4;
    const int l16  = lane & 15;
    const int s7   = l16 & 7;
    const int koff0 = (quad ^ s7) * 16;
    const int koff1 = ((quad + 4) ^ s7) * 16;
    const int hi8  = l16 >> 3;

    f32x4 acc[4][4];
#pragma unroll
    for (int i = 0; i < 4; ++i)
#pragma unroll
        for (int j = 0; j < 4; ++j)
            acc[i][j] = (f32x4){0.f, 0.f, 0.f, 0.f};
    f32x4 wacc[2];
    wacc[0] = (f32x4){0.f, 0.f, 0.f, 0.f};
    wacc[1] = (f32x4){0.f, 0.f, 0.f, 0.f};

    const int NT = K >> 6;

    // chunk t: t<17 -> A rows m0-8+t*8+srow (clamped); t>=17 -> B rows
    // n0+(t-17)*8+srow. lane l -> slot l*16B, global colblk (l&7)^(l>>3).
    auto STAGE = [&](int bufoff, int k0) {
#pragma unroll
        for (int i = 0; i < 9; ++i) {
            const int t = wave + i * 4;
            if (t < 33) {
                const unsigned short* g;
                if (t < 17) {
                    int gr = m0 - 8 + t * 8 + srow;
                    if (gr < 0) gr = 0;                 // mt==0 warm clamp
                    g = A + (size_t)gr * K + (k0 + scol);
                } else {
                    const int gr = n0 + (t - 17) * 8 + srow;
                    g = Bt + (size_t)gr * K + (k0 + scol);
                }
                __builtin_amdgcn_global_load_lds(
                    (const __attribute__((address_space(1))) void*)g,
                    (__attribute__((address_space(3))) void*)
                        (smem + bufoff + t * 1024 + lane * 16),
                    16, 0, 0);
            }
        }
    };

    STAGE(0, 0);
    __syncthreads();                     // implicit vmcnt(0) drain

    for (int t = 0; t < NT; ++t) {
        const int cur = (t & 1) * 33792;
        if (t + 1 < NT)
            STAGE((~t & 1) * 33792, (t + 1) * 64);   // flies under MFMAs

        const char* base = smem + cur;
#pragma unroll
        for (int kk = 0; kk < 2; ++kk) {
            const int co = kk ? koff1 : koff0;
            bf16x8 af[4], bfr[4], aw, bw0, bw1;
            aw = *(const bf16x8*)(base + hi8 * 1024 + s7 * 128 + co);
#pragma unroll
            for (int im = 0; im < 4; ++im)
                af[im] = *(const bf16x8*)(base +
                    (1 + wm * 8 + im * 2 + hi8) * 1024 + s7 * 128 + co);
#pragma unroll
            for (int in = 0; in < 4; ++in)
                bfr[in] = *(const bf16x8*)(base +
                    (17 + wn * 8 + in * 2 + hi8) * 1024 + s7 * 128 + co);
            bw0 = *(const bf16x8*)(base +
                    (17 + (wave * 2 + 0) * 2 + hi8) * 1024 + s7 * 128 + co);
            bw1 = *(const bf16x8*)(base +
                    (17 + (wave * 2 + 1) * 2 + hi8) * 1024 + s7 * 128 + co);
            wacc[0] = __builtin_amdgcn_mfma_f32_16x16x32_bf16(aw, bw0, wacc[0], 0, 0, 0);
            wacc[1] = __builtin_amdgcn_mfma_f32_16x16x32_bf16(aw, bw1, wacc[1], 0, 0, 0);
#pragma unroll
            for (int im = 0; im < 4; ++im)
#pragma unroll
                for (int in = 0; in < 4; ++in)
                    acc[im][in] = __builtin_amdgcn_mfma_f32_16x16x32_bf16(
                        af[im], bfr[in], acc[im][in], 0, 0, 0);
        }
        __syncthreads();                 // drains vmcnt incl. next-tile stage
    }

    // ---- epilogue: S (bf16) -> LDS, stride 132 (quads on banks +0/8/16/24)
    // LDS row 0..7 = warm rows (global m0-8..m0-1); row 8+r = global m0+r.
    unsigned short* Sl = (unsigned short*)smem;
#pragma unroll
    for (int im = 0; im < 4; ++im)
#pragma unroll
        for (int in = 0; in < 4; ++in) {
            const int col = wn * 64 + in * 16 + l16;
#pragma unroll
            for (int r = 0; r < 4; ++r) {
                const int row = 8 + wm * 64 + im * 16 + quad * 4 + r;
                Sl[row * 132 + col] = f2bf(acc[im][in][r]);
            }
        }
    if (quad < 2) {                      // warm rows 0..7
#pragma unroll
        for (int j = 0; j < 2; ++j) {
            const int wcol = (wave * 2 + j) * 16 + l16;
#pragma unroll
            for (int r = 0; r < 4; ++r)
                Sl[(quad * 4 + r) * 132 + wcol] = f2bf(wacc[j][r]);
        }
    }
    __syncthreads();

    // ---- in-block scan: 128 cols x 2 row-halves of 64 ----
    const int c = tid & 127;
    const int q = tid >> 7;
    const float aa = Ad[n0 + c];
    float y = 0.f;
    if (mt != 0 || q != 0) {
#pragma unroll
        for (int i = 0; i < 8; ++i)      // 8 rows before this half
            y = fmaf(aa, y, bf2f(Sl[(q * 64 + i) * 132 + c]));
    }
    const size_t ob = (size_t)(m0 + q * 64) * N + n0 + c;
    const unsigned short* Sr = Sl + (8 + q * 64) * 132 + c;
    for (int t = 0; t < 64; ++t) {
        y = fmaf(aa, y, bf2f(Sr[t * 132]));
        out[ob + (size_t)t * N] = y;
    }
}

// ---------------- tier-2 GEMM: 256x128, split-K=2, bf16 out (proven) --------

__global__ __launch_bounds__(256, 2) void gemm_sk_bf16out(
    const unsigned short* __restrict__ A,
    const unsigned short* __restrict__ Bt,
    unsigned short* __restrict__ S0, unsigned short* __restrict__ S1,
    int M, int N, int K, int gridM, int gridN)
{
    __shared__ __attribute__((aligned(16))) unsigned short sA[256 * 64];
    __shared__ __attribute__((aligned(16))) unsigned short sB[128 * 64];

    const int tid  = threadIdx.x;
    const int wave = tid >> 6;
    const int lane = tid & 63;

    int b = blockIdx.x;
    int mt, nt, kt;
    if ((gridM & 7) == 0) {
        int x = b & 7, g = b >> 3;
        int mPerX = gridM >> 3;
        int ml = g % mPerX, g2 = g / mPerX;
        nt = g2 % gridN;
        kt = g2 / gridN;
        mt = x * mPerX + ml;
    } else {
        mt = b % gridM;
        nt = (b / gridM) % gridN;
        kt = b / (gridM * gridN);
    }
    const int m0 = mt * 256;
    const int n0 = nt * 128;
    const int ksize = K / 2;
    const int kbase = kt * ksize;

    const int srow = lane >> 3;
    const int scol = ((lane & 7) ^ srow) * 8;

    const int quad = lane >> 4;
    const int l16  = lane & 15;
    const int wm = wave >> 1;
    const int wn = wave & 1;
    const int s7 = l16 & 7;
    const int c0 = (quad ^ s7) * 16;
    const int c1 = ((quad + 4) ^ s7) * 16;

    f32x4 acc[8][4];
#pragma unroll
    for (int i = 0; i < 8; ++i)
#pragma unroll
        for (int j = 0; j < 4; ++j)
            acc[i][j] = (f32x4){0.f, 0.f, 0.f, 0.f};

    const unsigned short* Ab = A  + (size_t)m0 * K;
    const unsigned short* Bb = Bt + (size_t)n0 * K;

    const int rA = (wm * 16 + (l16 >> 3)) * 1024 + s7 * 128;
    const int rB = (wn * 8  + (l16 >> 3)) * 1024 + s7 * 128;

    for (int k0 = kbase; k0 < kbase + ksize; k0 += 64) {
#pragma unroll
        for (int i = 0; i < 8; ++i) {
            const int t = wave * 8 + i;
            const unsigned short* ga = Ab + (size_t)(t * 8 + srow) * K + (k0 + scol);
            __builtin_amdgcn_global_load_lds(
                (const __attribute__((address_space(1))) void*)ga,
                (__attribute__((address_space(3))) void*)(sA + t * 512),
                16, 0, 0);
        }
#pragma unroll
        for (int i = 0; i < 4; ++i) {
            const int t = wave * 4 + i;
            const unsigned short* gb = Bb + (size_t)(t * 8 + srow) * K + (k0 + scol);
            __builtin_amdgcn_global_load_lds(
                (const __attribute__((address_space(1))) void*)gb,
                (__attribute__((address_space(3))) void*)(sB + t * 512),
                16, 0, 0);
        }
        __syncthreads();

#pragma unroll
        for (int kk = 0; kk < 2; ++kk) {
            const int co = kk ? c1 : c0;
            bf16x8 af[8], bfr[4];
#pragma unroll
            for (int im = 0; im < 8; ++im)
                af[im] = *(const bf16x8*)((const char*)sA + rA + im * 2048 + co);
#pragma unroll
            for (int in = 0; in < 4; ++in)
                bfr[in] = *(const bf16x8*)((const char*)sB + rB + in * 2048 + co);
#pragma unroll
            for (int im = 0; im < 8; ++im)
#pragma unroll
                for (int in = 0; in < 4; ++in)
                    acc[im][in] = __builtin_amdgcn_mfma_f32_16x16x32_bf16(
                        af[im], bfr[in], acc[im][in], 0, 0, 0);
        }
        __syncthreads();
    }

    unsigned short* __restrict__ S = (kt == 0) ? S0 : S1;
#pragma unroll
    for (int im = 0; im < 8; ++im) {
#pragma unroll
        for (int in = 0; in < 4; ++in) {
            int col = n0 + wn * 64 + in * 16 + l16;
#pragma unroll
            for (int r = 0; r < 4; ++r) {
                int row = m0 + wm * 128 + im * 16 + quad * 4 + r;
                S[(size_t)row * N + col] = f2bf(acc[im][in][r]);
            }
        }
    }
}

// ---------------- mid-tier GEMM (fp32 out, non-split; round-3 proven) -------

__device__ __forceinline__ void stage_tile128(
    const unsigned short* __restrict__ Ab, const unsigned short* __restrict__ Bb,
    unsigned short* sAp, unsigned short* sBp,
    int wave, int srow, int scol, int k0, int K)
{
#pragma unroll
    for (int i = 0; i < 4; ++i) {
        const int t = wave * 4 + i;
        const unsigned short* ga = Ab + (size_t)(t * 8 + srow) * K + (k0 + scol);
        __builtin_amdgcn_global_load_lds(
            (const __attribute__((address_space(1))) void*)ga,
            (__attribute__((address_space(3))) void*)(sAp + t * 512),
            16, 0, 0);
        const unsigned short* gb = Bb + (size_t)(t * 8 + srow) * K + (k0 + scol);
        __builtin_amdgcn_global_load_lds(
            (const __attribute__((address_space(1))) void*)gb,
            (__attribute__((address_space(3))) void*)(sBp + t * 512),
            16, 0, 0);
    }
}

__global__ __launch_bounds__(256, 4) void gemm_f32out(
    const unsigned short* __restrict__ A,
    const unsigned short* __restrict__ Bt,
    float* __restrict__ C, int M, int N, int K, int gridM)
{
    __shared__ __attribute__((aligned(16))) unsigned short sA[128 * 64];
    __shared__ __attribute__((aligned(16))) unsigned short sB[128 * 64];

    const int tid  = threadIdx.x;
    const int wave = tid >> 6;
    const int lane = tid & 63;

    int b = blockIdx.x;
    int mt, nt;
    if ((gridM & 7) == 0) {
        int x = b & 7, g = b >> 3;
        int mPerX = gridM >> 3;
        mt = x * mPerX + (g % mPerX);
        nt = g / mPerX;
    } else {
        mt = b % gridM;
        nt = b / gridM;
    }
    const int m0 = mt * 128;
    const int n0 = nt * 128;

    const int srow = lane >> 3;
    const int scol = ((lane & 7) ^ srow) * 8;
    const int quad = lane >> 4;
    const int l16  = lane & 15;
    const int wm = wave >> 1;
    const int wn = wave & 1;
    const int s7 = l16 & 7;
    const int rbaseA = (wm * 8 + (l16 >> 3)) * 1024 + s7 * 128;
    const int rbaseB = (wn * 8 + (l16 >> 3)) * 1024 + s7 * 128;
    const int coff0 = (quad ^ s7) * 16;
    const int coff1 = ((quad + 4) ^ s7) * 16;

    f32x4 acc[4][4];
#pragma unroll
    for (int i = 0; i < 4; ++i)
#pragma unroll
        for (int j = 0; j < 4; ++j)
            acc[i][j] = (f32x4){0.f, 0.f, 0.f, 0.f};

    const unsigned short* Ab = A  + (size_t)m0 * K;
    const unsigned short* Bb = Bt + (size_t)n0 * K;

    for (int k0 = 0; k0 < K; k0 += 64) {
        stage_tile128(Ab, Bb, sA, sB, wave, srow, scol, k0, K);
        __syncthreads();
        bf16x8 af[2][4], bfr[2][4];
#pragma unroll
        for (int t = 0; t < 4; ++t) {
            const char* pa = (const char*)sA + rbaseA + t * 2048;
            af[0][t]  = *(const bf16x8*)(pa + coff0);
            af[1][t]  = *(const bf16x8*)(pa + coff1);
            const char* pb = (const char*)sB + rbaseB + t * 2048;
            bfr[0][t] = *(const bf16x8*)(pb + coff0);
            bfr[1][t] = *(const bf16x8*)(pb + coff1);
        }
#pragma unroll
        for (int kk = 0; kk < 2; ++kk)
#pragma unroll
            for (int im = 0; im < 4; ++im)
#pragma unroll
                for (int in = 0; in < 4; ++in)
                    acc[im][in] = __builtin_amdgcn_mfma_f32_16x16x32_bf16(
                        af[kk][im], bfr[kk][in], acc[im][in], 0, 0, 0);
        __syncthreads();
    }

#pragma unroll
    for (int im = 0; im < 4; ++im)
#pragma unroll
        for (int in = 0; in < 4; ++in) {
            int col = n0 + wn * 64 + in * 16 + l16;
#pragma unroll
            for (int r = 0; r < 4; ++r) {
                int row = m0 + wm * 64 + im * 16 + quad * 4 + r;
                C[(size_t)row * N + col] = acc[im][in][r];
            }
        }
}

// ---------------- scan (split-K fallback path) ----------------

__global__ void scan_splitk_bf16(const unsigned short* __restrict__ S0,
                                 const unsigned short* __restrict__ S1,
                                 const float* __restrict__ a_diag,
                                 float* __restrict__ out,
                                 int H2, int chunk) {
    int tid = blockIdx.x * blockDim.x + threadIdx.x;
    int hp = tid % H2, c = tid / H2;
    float2 av = ((const float2*)a_diag)[hp];
    const ushort2* S0v = (const ushort2*)S0;
    const ushort2* S1v = (const ushort2*)S1;
    float2* outv = (float2*)out;

    float y0 = 0.f, y1 = 0.f;
    if (c > 0) {
        size_t r0 = (size_t)c * chunk - 8;
#pragma unroll
        for (int i = 0; i < 8; ++i) {
            size_t idx = (r0 + i) * H2 + hp;
            ushort2 u = S0v[idx], w = S1v[idx];
            y0 = fmaf(av.x, y0, bf2f(u.x) + bf2f(w.x));
            y1 = fmaf(av.y, y1, bf2f(u.y) + bf2f(w.y));
        }
    }
    size_t idx = (size_t)c * chunk * H2 + hp;
    ushort2 u = S0v[idx], w = S1v[idx];
    for (int t = 0; t < chunk - 1; ++t) {
        size_t idx2 = idx + H2;
        ushort2 un = S0v[idx2], wn = S1v[idx2];
        y0 = fmaf(av.x, y0, bf2f(u.x) + bf2f(w.x));
        y1 = fmaf(av.y, y1, bf2f(u.y) + bf2f(w.y));
        outv[idx] = make_float2(y0, y1);
        u = un; w = wn; idx = idx2;
    }
    y0 = fmaf(av.x, y0, bf2f(u.x) + bf2f(w.x));
    y1 = fmaf(av.y, y1, bf2f(u.y) + bf2f(w.y));
    outv[idx] = make_float2(y0, y1);
}

// ---------------- mid-tier scan (fp32 S in out, in-place) --------------

__global__ void scan_init_kernel(const float* __restrict__ S,
                                 const float* __restrict__ a_diag,
                                 float* __restrict__ yinit,
                                 int H, int chunk, int W) {
    int tid = blockIdx.x * blockDim.x + threadIdx.x;
    int h = tid % H, c = tid / H;
    float a = a_diag[h];
    float y = 0.f;
    if (c > 0) {
        int t0 = c * chunk;
        for (int t = t0 - W; t < t0; ++t)
            y = fmaf(a, y, S[(size_t)t * H + h]);
    }
    yinit[(size_t)c * H + h] = y;
}

__global__ void scan_run_kernel(const float* __restrict__ yinit,
                                const float* __restrict__ a_diag,
                                float* __restrict__ out,
                                int H, int chunk) {
    int tid = blockIdx.x * blockDim.x + threadIdx.x;
    int h = tid % H, c = tid / H;
    float a = a_diag[h];
    float y = yinit[(size_t)c * H + h];
    size_t base = (size_t)c * chunk * H + h;
    float s = out[base];
#pragma unroll 4
    for (int t = 0; t < chunk - 1; ++t) {
        float snext = out[base + (size_t)(t + 1) * H];
        y = fmaf(a, y, s);
        out[base + (size_t)t * H] = y;
        s = snext;
    }
    y = fmaf(a, y, s);
    out[base + (size_t)(chunk - 1) * H] = y;
}

// ---------------- fallback (tiny ws): correct but slow ----------------

__global__ void gemm_fallback(const float* __restrict__ X, const float* __restrict__ B,
                              float* __restrict__ C, int M, int N, int K) {
    __shared__ float sA[16][17];
    __shared__ float sB[16][17];
    int tx = threadIdx.x, ty = threadIdx.y;
    int row = blockIdx.y * 16 + ty, col = blockIdx.x * 16 + tx;
    float acc = 0.f;
    for (int k0 = 0; k0 < K; k0 += 16) {
        sA[ty][tx] = (row < M && k0 + tx < K) ? X[(size_t)row * K + k0 + tx] : 0.f;
        sB[ty][tx] = (k0 + ty < K && col < N) ? B[(size_t)(k0 + ty) * N + col] : 0.f;
        __syncthreads();
#pragma unroll
        for (int kk = 0; kk < 16; ++kk) acc += sA[ty][kk] * sB[kk][tx];
        __syncthreads();
    }
    if (row < M && col < N) C[(size_t)row * N + col] = acc;
}

__global__ void scan_serial(float* __restrict__ out, const float* __restrict__ a_diag,
                            int T, int H) {
    int h = blockIdx.x * blockDim.x + threadIdx.x;
    if (h >= H) return;
    float a = a_diag[h], y = 0.f;
    for (int t = 0; t < T; ++t) {
        y = fmaf(a, y, out[(size_t)t * H + h]);
        out[(size_t)t * H + h] = y;
    }
}

// ---------------- launch ----------------

extern "C" void kernel_launch(void* const* d_in, const int* in_sizes, int n_in,
                              void* d_out, int out_size, void* d_ws, size_t ws_size,
                              hipStream_t stream) {
    const float* x = (const float*)d_in[0];   // (T,H)
    const float* a = (const float*)d_in[1];   // (H,)
    const float* b = (const float*)d_in[2];   // (H,H)
    float* out = (float*)d_out;               // (T,H)

    const int H = in_sizes[1];
    const int T = in_sizes[0] / H;
    const int M = T, N = H, K = H;

    const int CHUNK = 16, W = 12;

    size_t xbf_elems = (size_t)M * K;
    size_t bt_elems  = (size_t)N * K;
    size_t MN = (size_t)M * N;
    int nchunks = (T % CHUNK == 0) ? T / CHUNK : 0;

    size_t need_fused = (xbf_elems + bt_elems) * 2 + 256;
    size_t need_sk  = (xbf_elems + bt_elems + 2 * MN) * 2 + 256;
    size_t need_mid = xbf_elems * 2 + bt_elems * 2 + 256;

    bool shape_ok = (M % 128 == 0) && (N % 128 == 0) && (K % 128 == 0) &&
                    (H % 32 == 0) && nchunks > 0 && ((xbf_elems % 4) == 0) &&
                    (((size_t)nchunks * H) % 256 == 0);
    int gridMf = M / 128;
    int gridM  = (M % 256 == 0) ? M / 256 : 0;
    int gridN  = N / 128;

    int n4 = (int)(xbf_elems / 4);
    int castBlocks = (n4 + 255) / 256;
    int transBlocks = (H % 32 == 0) ? (H / 32) * (H / 32) : 0;

    int H2 = H / 2;
    size_t nth2 = (size_t)nchunks * H2;

    bool fused_ok = (M % 128 == 0) && (N % 128 == 0) && (K % 64 == 0) &&
                    (K >= 128) && (H % 32 == 0) && ((xbf_elems % 4) == 0) &&
                    ws_size >= need_fused;

    if (fused_ok) {
        // tier-1: fused full-K GEMM + in-block scan (no S materialization)
        unsigned short* Xbf = (unsigned short*)d_ws;
        unsigned short* Bt  = Xbf + xbf_elems;

        static bool gfattr = false;
        if (!gfattr) {
            (void)hipFuncSetAttribute((const void*)gemm_scan_fused,
                                      hipFuncAttributeMaxDynamicSharedMemorySize,
                                      67584);
            gfattr = true;
        }

        prep_kernel<<<castBlocks + transBlocks, 256, 0, stream>>>(
            x, Xbf, n4, b, Bt, H, castBlocks);

        gemm_scan_fused<<<(M / 128) * (N / 128), 256, 67584, stream>>>(
            Xbf, Bt, a, out, M, N, K, M / 128);
    } else if (shape_ok && gridM > 0 && (gridM % 8 == 0) && (H % 4 == 0) &&
               (nth2 % 256 == 0) && ws_size >= need_sk) {
        // tier-2: 256x128 tiles, split-K=2, bf16 partials, race-free scan
        unsigned short* Xbf = (unsigned short*)d_ws;
        unsigned short* Bt  = Xbf + xbf_elems;
        unsigned short* S0  = Bt + bt_elems;
        unsigned short* S1  = S0 + MN;

        prep_kernel<<<castBlocks + transBlocks, 256, 0, stream>>>(
            x, Xbf, n4, b, Bt, H, castBlocks);

        gemm_sk_bf16out<<<gridM * gridN * 2, 256, 0, stream>>>(
            Xbf, Bt, S0, S1, M, N, K, gridM, gridN);

        scan_splitk_bf16<<<(int)(nth2 / 256), 256, 0, stream>>>(
            S0, S1, a, out, H2, CHUNK);
    } else if (shape_ok && ws_size >= need_mid &&
               ((size_t)nchunks * H * 4 <= xbf_elems * 2)) {
        unsigned short* Xbf = (unsigned short*)d_ws;
        unsigned short* Bt  = Xbf + xbf_elems;
        float* yinit = (float*)d_ws;   // aliases Xbf: dead after gemm reads it

        prep_kernel<<<castBlocks + transBlocks, 256, 0, stream>>>(
            x, Xbf, n4, b, Bt, H, castBlocks);

        gemm_f32out<<<gridMf * gridN, 256, 0, stream>>>(
            Xbf, Bt, out, M, N, K, gridMf);

        int nth = nchunks * H;
        scan_init_kernel<<<nth / 256, 256, 0, stream>>>(out, a, yinit, H, CHUNK, W);
        scan_run_kernel<<<nth / 256, 256, 0, stream>>>(yinit, a, out, H, CHUNK);
    } else {
        dim3 tb(16, 16), tg((N + 15) / 16, (M + 15) / 16);
        gemm_fallback<<<tg, tb, 0, stream>>>(x, b, out, M, N, K);
        scan_serial<<<(H + 255) / 256, 256, 0, stream>>>(out, a, T, H);
    }
}